// Round 9
// baseline (157.170 us; speedup 1.0000x reference)
//
#include <hip/hip_runtime.h>
#include <hip/hip_bf16.h>

// PAM module R15: q/k/v 1x1 projections -> FP8 MFMA attention -> gamma*out + x.
// R14 post-mortem (WIN, 97.4->73.8): byte-wall theory confirmed (FETCH halved,
// time -24%). Now below the ~33 B/cyc/CU byte wall (23 B/cyc) -> remaining
// stall is V load-use distance (~1 FUSED phase ~250cy < L2/L3 latency) plus
// VALU work (16 exp2 + 16 lpart adds). R15:
//   (a) V register ping-pong vfA/vfB -> load-use distance ~2 half-steps (~700cy)
//   (b) l via MFMA: lacc[ni] = mfma(ones_fp8, pf[ni], lacc) -- P column-sums on
//       the matrix pipe; kills 16 VALU adds/tile + end shfl-reduce. l now sums
//       the SAME quantized P used in the numerator (more consistent normalize).
// Reg budget: ~119 arch + ~104 acc = 223 < 256 -> still 2 waves/SIMD.
//
// Workspace layouts (fp8, frag-chunk = 64 lanes x 8B = 512B, paired to 1KB):
//   qf8[b][strip32]: pair (ni*2+kcp)*1024 + lane*16 + (kc&1)*8    4MB
//   kt8[b][tile128]: pair (mb*2+kcp)*1024 + lane*16 + (kc&1)*8    4MB (16KB/tile)
//   vt8[b][tile128]: pair (cbp*4+wq)*1024 + lane*16 + (cb&1)*8    4MB (16KB/tile)

typedef __bf16 v8bf __attribute__((ext_vector_type(8)));
typedef float  v4f  __attribute__((ext_vector_type(4)));
typedef unsigned long long u64;

#define B_ 8
#define C_ 128
#define N_ 4096

// Swizzled LDS offset (in shorts) for proj's 128x160 tiles (R9).
#define SWZ(R, COLS) ((R) * 160 + (((((COLS) >> 3) ^ (((R) >> 2) & 15))) << 3) + ((COLS) & 7))

static __device__ __forceinline__ unsigned short f2bf_rne(float f) {
    union { float f; unsigned u; } v; v.f = f;
    return (unsigned short)((v.u + 0x7fffu + ((v.u >> 16) & 1u)) >> 16);
}

// 8 bf16 (from sc scratch) -> 8 fp8 e4m3 bytes. Element order preserved.
static __device__ __forceinline__ u64 bf8pack(uint4 s) {
    float f[8];
    #pragma unroll
    for (int j = 0; j < 8; ++j) {
        unsigned hs = (j & 1) ? ((&s.x)[j >> 1] >> 16) : ((&s.x)[j >> 1] & 0xffffu);
        union { unsigned u; float f; } t; t.u = hs << 16; f[j] = t.f;
    }
    int lo = __builtin_amdgcn_cvt_pk_fp8_f32(f[0], f[1], 0, false);
    lo     = __builtin_amdgcn_cvt_pk_fp8_f32(f[2], f[3], lo, true);
    int hi = __builtin_amdgcn_cvt_pk_fp8_f32(f[4], f[5], 0, false);
    hi     = __builtin_amdgcn_cvt_pk_fp8_f32(f[6], f[7], hi, true);
    return (u64)(unsigned)lo | ((u64)(unsigned)hi << 32);
}

// ---------------------------------------------------------------------------
// Kernel 1: q/k/v projections (R14 verbatim: bf16 MFMA + swizzled scratch,
// fp8 writeback).
// ---------------------------------------------------------------------------
__global__ __launch_bounds__(256, 2) void proj_kernel(
    const float* __restrict__ x,
    const float* __restrict__ dw_q, const float* __restrict__ pw_q,
    const float* __restrict__ dw_k, const float* __restrict__ pw_k,
    const float* __restrict__ dw_v, const float* __restrict__ pw_v,
    unsigned char* __restrict__ qf8, unsigned char* __restrict__ kt8,
    unsigned char* __restrict__ vt8)
{
    __shared__ unsigned short xT[128 * 160];  // xT[n][c], swizzled
    __shared__ unsigned short Ws[128 * 160];  // W[o][c], swizzled; reused as store scratch

    const int bid = blockIdx.x;
    const int bb  = bid & 7;
    const int t   = (bid >> 3) & 31;
    const int pp  = bid >> 8;            // 0:q 1:k 2:v
    const int n0  = t * 128;
    const int tid = threadIdx.x;
    const int w    = tid >> 6;
    const int lane = tid & 63;
    const int quad = lane >> 4;
    const int l16  = lane & 15;

    #pragma unroll
    for (int k = 0; k < 16; ++k) {
        const int idx = tid + k * 256;
        const int c  = idx >> 5;
        const int nq = idx & 31;
        float4 f = *(const float4*)(x + ((size_t)(bb * C_ + c)) * N_ + n0 + nq * 4);
        xT[SWZ(nq * 4 + 0, c)] = f2bf_rne(f.x);
        xT[SWZ(nq * 4 + 1, c)] = f2bf_rne(f.y);
        xT[SWZ(nq * 4 + 2, c)] = f2bf_rne(f.z);
        xT[SWZ(nq * 4 + 3, c)] = f2bf_rne(f.w);
    }
    const float* pw = (pp == 0) ? pw_q : (pp == 1) ? pw_k : pw_v;
    const float* dw = (pp == 0) ? dw_q : (pp == 1) ? dw_k : dw_v;
    const float qs = (pp == 0) ? 1.4426950408889634f : 1.0f;   // exp2 softmax
    #pragma unroll
    for (int k = 0; k < 16; ++k) {
        const int idx = tid + k * 256;
        const int o  = idx >> 5;
        const int c4 = (idx & 31) * 4;
        float4 p4 = *(const float4*)(pw + o * 128 + c4);
        float4 d4 = *(const float4*)(dw + c4);
        unsigned lo = (unsigned)f2bf_rne(p4.x * d4.x * qs) | ((unsigned)f2bf_rne(p4.y * d4.y * qs) << 16);
        unsigned hi = (unsigned)f2bf_rne(p4.z * d4.z * qs) | ((unsigned)f2bf_rne(p4.w * d4.w * qs) << 16);
        *(unsigned long long*)&Ws[SWZ(o, c4)] =
            (unsigned long long)lo | ((unsigned long long)hi << 32);
    }
    __syncthreads();

    const unsigned short* As = (pp < 2) ? xT : Ws;
    const unsigned short* Bs = (pp < 2) ? Ws : xT;

    v4f acc[2][8];
    #pragma unroll
    for (int i = 0; i < 2; ++i)
        #pragma unroll
        for (int j = 0; j < 8; ++j)
            acc[i][j] = (v4f){0.f, 0.f, 0.f, 0.f};

    #pragma unroll
    for (int kc = 0; kc < 4; ++kc) {
        v8bf av[2];
        #pragma unroll
        for (int i = 0; i < 2; ++i)
            av[i] = *(const v8bf*)&As[SWZ(w * 32 + i * 16 + l16, kc * 32 + quad * 8)];
        #pragma unroll
        for (int cb = 0; cb < 8; ++cb) {
            v8bf bv = *(const v8bf*)&Bs[SWZ(cb * 16 + l16, kc * 32 + quad * 8)];
            acc[0][cb] = __builtin_amdgcn_mfma_f32_16x16x32_bf16(av[0], bv, acc[0][cb], 0, 0, 0);
            acc[1][cb] = __builtin_amdgcn_mfma_f32_16x16x32_bf16(av[1], bv, acc[1][cb], 0, 0, 0);
        }
    }
    __syncthreads();

    unsigned short* sc = Ws;
    #pragma unroll
    for (int mi = 0; mi < 2; ++mi)
        #pragma unroll
        for (int cb = 0; cb < 8; ++cb)
            #pragma unroll
            for (int r = 0; r < 4; ++r)
                sc[SWZ(w * 32 + mi * 16 + quad * 4 + r, cb * 16 + l16)] =
                    f2bf_rne(acc[mi][cb][r]);
    __syncthreads();

    if (pp == 0) {
        unsigned char* dst = qf8 + (size_t)bb * 524288;
        #pragma unroll
        for (int p = 0; p < 8; ++p) {
            const int g     = p * 4 + w;
            const int strip = g >> 4, ni = (g >> 2) & 3, kc = g & 3;
            uint4 sv = *(const uint4*)&sc[SWZ(strip * 64 + ni * 16 + l16, kc * 32 + quad * 8)];
            *(u64*)(dst + (size_t)(t * 4 + strip * 2 + (ni >> 1)) * 4096
                        + ((ni & 1) * 2 + (kc >> 1)) * 1024 + lane * 16 + (kc & 1) * 8)
                = bf8pack(sv);
        }
    } else if (pp == 1) {
        unsigned char* dst = kt8 + (size_t)(bb * 32 + t) * 16384;
        #pragma unroll
        for (int p = 0; p < 8; ++p) {
            const int g  = p * 4 + w;
            const int mb = g >> 2, kc = g & 3;
            uint4 sv = *(const uint4*)&sc[SWZ(mb * 16 + l16, kc * 32 + quad * 8)];
            *(u64*)(dst + (mb * 2 + (kc >> 1)) * 1024 + lane * 16 + (kc & 1) * 8)
                = bf8pack(sv);
        }
    } else {
        unsigned char* dst = vt8 + (size_t)(bb * 32 + t) * 16384;
        #pragma unroll
        for (int p = 0; p < 8; ++p) {
            const int d   = p * 256 + tid;
            const int cb  = d >> 8;
            const int wqm = (d >> 6) & 3;
            const int q16 = (d >> 4) & 15;
            const int l   = d & 15;
            const int lnS = d & 63;
            uint4 sv = *(const uint4*)&sc[SWZ(cb * 16 + l, q16 * 8)];
            *(u64*)(dst + ((cb >> 1) * 4 + wqm) * 1024 + lnS * 16 + (cb & 1) * 8)
                = bf8pack(sv);
        }
    }
}

// ---------------------------------------------------------------------------
// Kernel 2: fp8 attention. grid 1024 = (b, 32-row n-strip). 256 thr / 4 waves;
// wave = m-quarter, full c=128, n=32. R7 dual-sacc schedule; K ping-pong 2
// ahead; V ping-pong 2 ahead (R15a); l via ones-MFMA (R15b).
// ---------------------------------------------------------------------------
#define MFMA8(A, B, C) __builtin_amdgcn_mfma_f32_16x16x32_fp8_fp8((long)(A), (long)(B), C, 0, 0, 0)
#define EXP2(X) __builtin_amdgcn_exp2f(X)
#define PK8(E0, E1, E2, E3, W) { \
    W = __builtin_amdgcn_cvt_pk_fp8_f32(E0, E1, 0, false); \
    W = __builtin_amdgcn_cvt_pk_fp8_f32(E2, E3, W, true); \
}

#define SPLIT16(U4, LO, HI) { \
    LO = (u64)(U4).x | ((u64)(U4).y << 32); \
    HI = (u64)(U4).z | ((u64)(U4).w << 32); \
}

#define LOADK(KF, TILE) { \
    const unsigned char* kp_ = kbase + (size_t)(TILE) * 16384; \
    _Pragma("unroll") \
    for (int mi_ = 0; mi_ < 2; ++mi_) \
        _Pragma("unroll") \
        for (int kcp_ = 0; kcp_ < 2; ++kcp_) { \
            uint4 u_ = *(const uint4*)(kp_ + (mi_ * 2 + kcp_) * 1024); \
            SPLIT16(u_, KF[mi_][kcp_ * 2], KF[mi_][kcp_ * 2 + 1]) \
        } \
}

#define LOADV(VF, TILE) { \
    const unsigned char* vp_ = vbase + (size_t)(TILE) * 16384; \
    _Pragma("unroll") \
    for (int cbp_ = 0; cbp_ < 4; ++cbp_) { \
        uint4 u_ = *(const uint4*)(vp_ + cbp_ * 4096); \
        SPLIT16(u_, VF[cbp_ * 2], VF[cbp_ * 2 + 1]) \
    } \
}

// P fragment for ni: gather 4-fp8 words from the two source quads. 2 bpermutes.
#define MKPF8(NI, PK0, PK1) { \
    int s_ = (quad < 2) ? PK0 : PK1; \
    u64 lo_ = (unsigned)__builtin_amdgcn_ds_bpermute(la, s_); \
    u64 hi_ = (unsigned)__builtin_amdgcn_ds_bpermute(lb, s_); \
    pf[NI] = lo_ | (hi_ << 32); \
}

#define SCOMP0(KF, SC) { \
    _Pragma("unroll") \
    for (int mi_ = 0; mi_ < 2; ++mi_) \
        _Pragma("unroll") \
        for (int ni_ = 0; ni_ < 2; ++ni_) { \
            v4f a_ = MFMA8(KF[mi_][0], qf[ni_][0], Z4v); \
            _Pragma("unroll") \
            for (int kc_ = 1; kc_ < 4; ++kc_) \
                a_ = MFMA8(KF[mi_][kc_], qf[ni_][kc_], a_); \
            SC[mi_][ni_] = a_; \
        } \
}

// softmax(SC_IN) hand-interleaved with the 16 S-MFMAs of the next tile.
// l accumulation moved to the matrix pipe: lacc[ni] += ones x pf[ni]
// (P column-sums; all 4 out regs identical).
#define FUSED(SC_IN, KF, SC_OUT) { \
    float e0_, e1_, e2_, e3_; \
    int pk00_, pk10_, pk01_, pk11_; \
    SC_OUT[0][0] = MFMA8(KF[0][0], qf[0][0], Z4v); \
    SC_OUT[0][1] = MFMA8(KF[0][0], qf[1][0], Z4v); \
    e0_ = EXP2(SC_IN[0][0][0]); e1_ = EXP2(SC_IN[0][0][1]); \
    e2_ = EXP2(SC_IN[0][0][2]); e3_ = EXP2(SC_IN[0][0][3]); \
    SC_OUT[0][0] = MFMA8(KF[0][1], qf[0][1], SC_OUT[0][0]); \
    SC_OUT[0][1] = MFMA8(KF[0][1], qf[1][1], SC_OUT[0][1]); \
    PK8(e0_, e1_, e2_, e3_, pk00_) \
    SC_OUT[0][0] = MFMA8(KF[0][2], qf[0][2], SC_OUT[0][0]); \
    SC_OUT[0][1] = MFMA8(KF[0][2], qf[1][2], SC_OUT[0][1]); \
    e0_ = EXP2(SC_IN[1][0][0]); e1_ = EXP2(SC_IN[1][0][1]); \
    e2_ = EXP2(SC_IN[1][0][2]); e3_ = EXP2(SC_IN[1][0][3]); \
    SC_OUT[0][0] = MFMA8(KF[0][3], qf[0][3], SC_OUT[0][0]); \
    SC_OUT[0][1] = MFMA8(KF[0][3], qf[1][3], SC_OUT[0][1]); \
    PK8(e0_, e1_, e2_, e3_, pk10_) \
    SC_OUT[1][0] = MFMA8(KF[1][0], qf[0][0], Z4v); \
    SC_OUT[1][1] = MFMA8(KF[1][0], qf[1][0], Z4v); \
    MKPF8(0, pk00_, pk10_) \
    lacc[0] = MFMA8(ones8, pf[0], lacc[0]); \
    SC_OUT[1][0] = MFMA8(KF[1][1], qf[0][1], SC_OUT[1][0]); \
    SC_OUT[1][1] = MFMA8(KF[1][1], qf[1][1], SC_OUT[1][1]); \
    e0_ = EXP2(SC_IN[0][1][0]); e1_ = EXP2(SC_IN[0][1][1]); \
    e2_ = EXP2(SC_IN[0][1][2]); e3_ = EXP2(SC_IN[0][1][3]); \
    SC_OUT[1][0] = MFMA8(KF[1][2], qf[0][2], SC_OUT[1][0]); \
    SC_OUT[1][1] = MFMA8(KF[1][2], qf[1][2], SC_OUT[1][1]); \
    PK8(e0_, e1_, e2_, e3_, pk01_) \
    SC_OUT[1][0] = MFMA8(KF[1][3], qf[0][3], SC_OUT[1][0]); \
    SC_OUT[1][1] = MFMA8(KF[1][3], qf[1][3], SC_OUT[1][1]); \
    e0_ = EXP2(SC_IN[1][1][0]); e1_ = EXP2(SC_IN[1][1][1]); \
    e2_ = EXP2(SC_IN[1][1][2]); e3_ = EXP2(SC_IN[1][1][3]); \
    PK8(e0_, e1_, e2_, e3_, pk11_) \
    MKPF8(1, pk01_, pk11_) \
    lacc[1] = MFMA8(ones8, pf[1], lacc[1]); \
}

#define PVOP(VF) { \
    _Pragma("unroll") \
    for (int ni_ = 0; ni_ < 2; ++ni_) \
        _Pragma("unroll") \
        for (int cb_ = 0; cb_ < 8; ++cb_) \
            oacc[cb_][ni_] = MFMA8(VF[cb_], pf[ni_], oacc[cb_][ni_]); \
}

__global__ __launch_bounds__(256, 2) void attn_kernel(
    const unsigned char* __restrict__ qf8, const unsigned char* __restrict__ kt8,
    const unsigned char* __restrict__ vt8, const float* __restrict__ x,
    const float* __restrict__ gamma, float* __restrict__ out)
{
    __shared__ float red[32 * 132];   // O reduction scratch [n][c] (+pad)
    __shared__ float l_s[4][32];

    const int bid = blockIdx.x;
    const int bb  = bid & 7;
    const int s   = bid >> 3;        // n-strip 0..127 (32 rows each)
    const int n0  = s * 32;
    const int tid = threadIdx.x;
    const int w    = tid >> 6;       // wave = m-quarter owner
    const int lane = tid & 63;
    const int quad = lane >> 4;
    const int l16  = lane & 15;

    // ---- Q fragments (n=32 strip): fp8, 16 VGPR, iteration-invariant
    u64 qf[2][4];
    {
        const unsigned char* qb = qf8 + (size_t)(bb * 128 + s) * 4096 + lane * 16;
        #pragma unroll
        for (int ni = 0; ni < 2; ++ni)
            #pragma unroll
            for (int kcp = 0; kcp < 2; ++kcp) {
                uint4 u = *(const uint4*)(qb + (ni * 2 + kcp) * 1024);
                SPLIT16(u, qf[ni][kcp * 2], qf[ni][kcp * 2 + 1])
            }
    }

    v4f oacc[8][2];  // [cb][ni] partial O over this wave's 32-m subset
    #pragma unroll
    for (int i = 0; i < 8; ++i)
        #pragma unroll
        for (int j = 0; j < 2; ++j)
            oacc[i][j] = (v4f){0.f, 0.f, 0.f, 0.f};
    v4f lacc[2] = {(v4f){0.f, 0.f, 0.f, 0.f}, (v4f){0.f, 0.f, 0.f, 0.f}};
    const v4f Z4v = {0.f, 0.f, 0.f, 0.f};
    const u64 ones8 = 0x3838383838383838ull;   // 8x fp8 e4m3 1.0

    const int la = ((((quad & 1) << 1) << 4) + l16) << 2;  // bpermute byte idx
    const int lb = la + 64;

    const unsigned char* kbase = kt8 + (size_t)(bb * 32) * 16384 + w * 4096 + lane * 16;
    const unsigned char* vbase = vt8 + (size_t)(bb * 32) * 16384 + w * 1024 + lane * 16;

    u64 kfA[2][4], kfB[2][4], vfA[8], vfB[8], pf[2];
    v4f sc0[2][2], sc1[2][2];

    LOADK(kfA, 0)
    LOADV(vfA, 0)
    LOADK(kfB, 1)
    LOADV(vfB, 1)
    SCOMP0(kfA, sc0)                 // S(0)

    for (int it = 0; it < 32; it += 2) {
        LOADK(kfA, (it + 2) & 31)    // K(t+2) in flight
        FUSED(sc0, kfB, sc1)         // softmax(t) || S(t+1)
        PVOP(vfA)                    // PV(t)
        LOADV(vfA, (it + 2) & 31)    // V(t+2): ~2 half-steps of distance
        LOADK(kfB, (it + 3) & 31)
        FUSED(sc1, kfA, sc0)         // softmax(t+1) || S(t+2)
        PVOP(vfB)                    // PV(t+1)
        LOADV(vfB, (it + 3) & 31)
    }

    // ---- softmax denominators: lacc rows are identical; col = lane&15.
    #pragma unroll
    for (int ni = 0; ni < 2; ++ni)
        if (lane < 16) l_s[w][ni * 16 + lane] = lacc[ni][0];

    // ---- O reduction across the 4 m-quarter waves
    for (int rw = 0; rw < 4; ++rw) {
        if (w == rw) {
            #pragma unroll
            for (int cb = 0; cb < 8; ++cb)
                #pragma unroll
                for (int ni = 0; ni < 2; ++ni) {
                    float* p = &red[(ni * 16 + l16) * 132 + cb * 16 + quad * 4];
                    if (rw == 0) *(v4f*)p = oacc[cb][ni];
                    else {
                        v4f tv = *(const v4f*)p;
                        tv += oacc[cb][ni];
                        *(v4f*)p = tv;
                    }
                }
        }
        __syncthreads();
    }

    // ---- epilogue: out = gamma * O / l + x  (thread: n = tid&31, c-group = tid>>5)
    const float g = gamma[0];
    const int   n = tid & 31;
    const int  cg = tid >> 5;        // 0..7
    const float li = 1.0f / (((l_s[0][n] + l_s[1][n]) + (l_s[2][n] + l_s[3][n])));
    #pragma unroll
    for (int j = 0; j < 16; ++j) {
        const int c = cg * 16 + j;
        const size_t idx = ((size_t)(bb * C_ + c)) * N_ + n0 + n;
        out[idx] = g * red[n * 132 + c] * li + x[idx];
    }
}

// ---------------------------------------------------------------------------
extern "C" void kernel_launch(void* const* d_in, const int* in_sizes, int n_in,
                              void* d_out, int out_size, void* d_ws, size_t ws_size,
                              hipStream_t stream)
{
    (void)in_sizes; (void)n_in; (void)out_size; (void)ws_size;
    const float* x     = (const float*)d_in[0];
    const float* dw_q  = (const float*)d_in[1];
    const float* pw_q  = (const float*)d_in[2];
    const float* dw_k  = (const float*)d_in[3];
    const float* pw_k  = (const float*)d_in[4];
    const float* dw_v  = (const float*)d_in[5];
    const float* pw_v  = (const float*)d_in[6];
    const float* gamma = (const float*)d_in[7];
    float* out = (float*)d_out;

    unsigned char* qf8 = (unsigned char*)d_ws;                         // 4 MB
    unsigned char* kt8 = qf8 + (size_t)B_ * N_ * C_;                   // +4 MB
    unsigned char* vt8 = kt8 + (size_t)B_ * N_ * C_;                   // +4 MB

    proj_kernel<<<dim3(768), dim3(256), 0, stream>>>(
        x, dw_q, pw_q, dw_k, pw_k, dw_v, pw_v, qf8, kt8, vt8);
    attn_kernel<<<dim3(1024), dim3(256), 0, stream>>>(
        qf8, kt8, vt8, x, gamma, out);
}

// Round 10
// 142.688 us; speedup vs baseline: 1.1015x; 1.1015x over previous
//
#include <hip/hip_runtime.h>
#include <hip/hip_bf16.h>

// PAM module R16: q/k/v 1x1 projections -> FP8 MFMA attention -> gamma*out + x.
// R15 post-mortem (REGRESSION 73.8->78.8): V ping-pong lengthened register
// dependence chains; l-via-MFMA put 2 extra MFMAs on the critical S->P->PV
// path. Both reverted -- R16 is R14 verbatim (best: attn 73.8, total 154.1)
// plus ONE isolated graft: T5 s_setprio(1) around the PV MFMA cluster.
// Regime check: T5 helps attn-like kernels with barrier-free in-loop waves
// (m191 +4-7%), hurts only lockstep structures (m190) -- this loop has zero
// barriers, 4 desynced waves/block. If null/negative, R14 is the floor.
//
// Workspace layouts (fp8, frag-chunk = 64 lanes x 8B = 512B, paired to 1KB):
//   qf8[b][strip32]: pair (ni*2+kcp)*1024 + lane*16 + (kc&1)*8    4MB
//   kt8[b][tile128]: pair (mb*2+kcp)*1024 + lane*16 + (kc&1)*8    4MB (16KB/tile)
//   vt8[b][tile128]: pair (cbp*4+wq)*1024 + lane*16 + (cb&1)*8    4MB (16KB/tile)

typedef __bf16 v8bf __attribute__((ext_vector_type(8)));
typedef float  v4f  __attribute__((ext_vector_type(4)));
typedef unsigned long long u64;

#define B_ 8
#define C_ 128
#define N_ 4096

// Swizzled LDS offset (in shorts) for proj's 128x160 tiles (R9).
#define SWZ(R, COLS) ((R) * 160 + (((((COLS) >> 3) ^ (((R) >> 2) & 15))) << 3) + ((COLS) & 7))

static __device__ __forceinline__ unsigned short f2bf_rne(float f) {
    union { float f; unsigned u; } v; v.f = f;
    return (unsigned short)((v.u + 0x7fffu + ((v.u >> 16) & 1u)) >> 16);
}

// 8 bf16 (from sc scratch) -> 8 fp8 e4m3 bytes. Element order preserved.
static __device__ __forceinline__ u64 bf8pack(uint4 s) {
    float f[8];
    #pragma unroll
    for (int j = 0; j < 8; ++j) {
        unsigned hs = (j & 1) ? ((&s.x)[j >> 1] >> 16) : ((&s.x)[j >> 1] & 0xffffu);
        union { unsigned u; float f; } t; t.u = hs << 16; f[j] = t.f;
    }
    int lo = __builtin_amdgcn_cvt_pk_fp8_f32(f[0], f[1], 0, false);
    lo     = __builtin_amdgcn_cvt_pk_fp8_f32(f[2], f[3], lo, true);
    int hi = __builtin_amdgcn_cvt_pk_fp8_f32(f[4], f[5], 0, false);
    hi     = __builtin_amdgcn_cvt_pk_fp8_f32(f[6], f[7], hi, true);
    return (u64)(unsigned)lo | ((u64)(unsigned)hi << 32);
}

// ---------------------------------------------------------------------------
// Kernel 1: q/k/v projections (R14 verbatim: bf16 MFMA + swizzled scratch,
// fp8 writeback).
// ---------------------------------------------------------------------------
__global__ __launch_bounds__(256, 2) void proj_kernel(
    const float* __restrict__ x,
    const float* __restrict__ dw_q, const float* __restrict__ pw_q,
    const float* __restrict__ dw_k, const float* __restrict__ pw_k,
    const float* __restrict__ dw_v, const float* __restrict__ pw_v,
    unsigned char* __restrict__ qf8, unsigned char* __restrict__ kt8,
    unsigned char* __restrict__ vt8)
{
    __shared__ unsigned short xT[128 * 160];  // xT[n][c], swizzled
    __shared__ unsigned short Ws[128 * 160];  // W[o][c], swizzled; reused as store scratch

    const int bid = blockIdx.x;
    const int bb  = bid & 7;
    const int t   = (bid >> 3) & 31;
    const int pp  = bid >> 8;            // 0:q 1:k 2:v
    const int n0  = t * 128;
    const int tid = threadIdx.x;
    const int w    = tid >> 6;
    const int lane = tid & 63;
    const int quad = lane >> 4;
    const int l16  = lane & 15;

    #pragma unroll
    for (int k = 0; k < 16; ++k) {
        const int idx = tid + k * 256;
        const int c  = idx >> 5;
        const int nq = idx & 31;
        float4 f = *(const float4*)(x + ((size_t)(bb * C_ + c)) * N_ + n0 + nq * 4);
        xT[SWZ(nq * 4 + 0, c)] = f2bf_rne(f.x);
        xT[SWZ(nq * 4 + 1, c)] = f2bf_rne(f.y);
        xT[SWZ(nq * 4 + 2, c)] = f2bf_rne(f.z);
        xT[SWZ(nq * 4 + 3, c)] = f2bf_rne(f.w);
    }
    const float* pw = (pp == 0) ? pw_q : (pp == 1) ? pw_k : pw_v;
    const float* dw = (pp == 0) ? dw_q : (pp == 1) ? dw_k : dw_v;
    const float qs = (pp == 0) ? 1.4426950408889634f : 1.0f;   // exp2 softmax
    #pragma unroll
    for (int k = 0; k < 16; ++k) {
        const int idx = tid + k * 256;
        const int o  = idx >> 5;
        const int c4 = (idx & 31) * 4;
        float4 p4 = *(const float4*)(pw + o * 128 + c4);
        float4 d4 = *(const float4*)(dw + c4);
        unsigned lo = (unsigned)f2bf_rne(p4.x * d4.x * qs) | ((unsigned)f2bf_rne(p4.y * d4.y * qs) << 16);
        unsigned hi = (unsigned)f2bf_rne(p4.z * d4.z * qs) | ((unsigned)f2bf_rne(p4.w * d4.w * qs) << 16);
        *(unsigned long long*)&Ws[SWZ(o, c4)] =
            (unsigned long long)lo | ((unsigned long long)hi << 32);
    }
    __syncthreads();

    const unsigned short* As = (pp < 2) ? xT : Ws;
    const unsigned short* Bs = (pp < 2) ? Ws : xT;

    v4f acc[2][8];
    #pragma unroll
    for (int i = 0; i < 2; ++i)
        #pragma unroll
        for (int j = 0; j < 8; ++j)
            acc[i][j] = (v4f){0.f, 0.f, 0.f, 0.f};

    #pragma unroll
    for (int kc = 0; kc < 4; ++kc) {
        v8bf av[2];
        #pragma unroll
        for (int i = 0; i < 2; ++i)
            av[i] = *(const v8bf*)&As[SWZ(w * 32 + i * 16 + l16, kc * 32 + quad * 8)];
        #pragma unroll
        for (int cb = 0; cb < 8; ++cb) {
            v8bf bv = *(const v8bf*)&Bs[SWZ(cb * 16 + l16, kc * 32 + quad * 8)];
            acc[0][cb] = __builtin_amdgcn_mfma_f32_16x16x32_bf16(av[0], bv, acc[0][cb], 0, 0, 0);
            acc[1][cb] = __builtin_amdgcn_mfma_f32_16x16x32_bf16(av[1], bv, acc[1][cb], 0, 0, 0);
        }
    }
    __syncthreads();

    unsigned short* sc = Ws;
    #pragma unroll
    for (int mi = 0; mi < 2; ++mi)
        #pragma unroll
        for (int cb = 0; cb < 8; ++cb)
            #pragma unroll
            for (int r = 0; r < 4; ++r)
                sc[SWZ(w * 32 + mi * 16 + quad * 4 + r, cb * 16 + l16)] =
                    f2bf_rne(acc[mi][cb][r]);
    __syncthreads();

    if (pp == 0) {
        unsigned char* dst = qf8 + (size_t)bb * 524288;
        #pragma unroll
        for (int p = 0; p < 8; ++p) {
            const int g     = p * 4 + w;
            const int strip = g >> 4, ni = (g >> 2) & 3, kc = g & 3;
            uint4 sv = *(const uint4*)&sc[SWZ(strip * 64 + ni * 16 + l16, kc * 32 + quad * 8)];
            *(u64*)(dst + (size_t)(t * 4 + strip * 2 + (ni >> 1)) * 4096
                        + ((ni & 1) * 2 + (kc >> 1)) * 1024 + lane * 16 + (kc & 1) * 8)
                = bf8pack(sv);
        }
    } else if (pp == 1) {
        unsigned char* dst = kt8 + (size_t)(bb * 32 + t) * 16384;
        #pragma unroll
        for (int p = 0; p < 8; ++p) {
            const int g  = p * 4 + w;
            const int mb = g >> 2, kc = g & 3;
            uint4 sv = *(const uint4*)&sc[SWZ(mb * 16 + l16, kc * 32 + quad * 8)];
            *(u64*)(dst + (mb * 2 + (kc >> 1)) * 1024 + lane * 16 + (kc & 1) * 8)
                = bf8pack(sv);
        }
    } else {
        unsigned char* dst = vt8 + (size_t)(bb * 32 + t) * 16384;
        #pragma unroll
        for (int p = 0; p < 8; ++p) {
            const int d   = p * 256 + tid;
            const int cb  = d >> 8;
            const int wqm = (d >> 6) & 3;
            const int q16 = (d >> 4) & 15;
            const int l   = d & 15;
            const int lnS = d & 63;
            uint4 sv = *(const uint4*)&sc[SWZ(cb * 16 + l, q16 * 8)];
            *(u64*)(dst + ((cb >> 1) * 4 + wqm) * 1024 + lnS * 16 + (cb & 1) * 8)
                = bf8pack(sv);
        }
    }
}

// ---------------------------------------------------------------------------
// Kernel 2: fp8 attention (R14 schedule verbatim + T5 setprio on PV cluster).
// grid 1024 = (b, 32-row n-strip). 256 thr / 4 waves; wave = m-quarter, full
// c=128, n=32. Dual-sacc pipeline: softmax(t) interleaved with S-MFMAs of
// t+1; K register ping-pong; V single-buffer.
// ---------------------------------------------------------------------------
#define MFMA8(A, B, C) __builtin_amdgcn_mfma_f32_16x16x32_fp8_fp8((long)(A), (long)(B), C, 0, 0, 0)
#define EXP2(X) __builtin_amdgcn_exp2f(X)
#define PK8(E0, E1, E2, E3, W) { \
    W = __builtin_amdgcn_cvt_pk_fp8_f32(E0, E1, 0, false); \
    W = __builtin_amdgcn_cvt_pk_fp8_f32(E2, E3, W, true); \
}

#define SPLIT16(U4, LO, HI) { \
    LO = (u64)(U4).x | ((u64)(U4).y << 32); \
    HI = (u64)(U4).z | ((u64)(U4).w << 32); \
}

#define LOADK(KF, TILE) { \
    const unsigned char* kp_ = kbase + (size_t)(TILE) * 16384; \
    _Pragma("unroll") \
    for (int mi_ = 0; mi_ < 2; ++mi_) \
        _Pragma("unroll") \
        for (int kcp_ = 0; kcp_ < 2; ++kcp_) { \
            uint4 u_ = *(const uint4*)(kp_ + (mi_ * 2 + kcp_) * 1024); \
            SPLIT16(u_, KF[mi_][kcp_ * 2], KF[mi_][kcp_ * 2 + 1]) \
        } \
}

#define LOADV(TILE) { \
    const unsigned char* vp_ = vbase + (size_t)(TILE) * 16384; \
    _Pragma("unroll") \
    for (int cbp_ = 0; cbp_ < 4; ++cbp_) { \
        uint4 u_ = *(const uint4*)(vp_ + cbp_ * 4096); \
        SPLIT16(u_, vf[cbp_ * 2], vf[cbp_ * 2 + 1]) \
    } \
}

// P fragment for ni: gather 4-fp8 words from the two source quads. 2 bpermutes.
#define MKPF8(NI, PK0, PK1) { \
    int s_ = (quad < 2) ? PK0 : PK1; \
    u64 lo_ = (unsigned)__builtin_amdgcn_ds_bpermute(la, s_); \
    u64 hi_ = (unsigned)__builtin_amdgcn_ds_bpermute(lb, s_); \
    pf[NI] = lo_ | (hi_ << 32); \
}

#define SCOMP0(KF, SC) { \
    _Pragma("unroll") \
    for (int mi_ = 0; mi_ < 2; ++mi_) \
        _Pragma("unroll") \
        for (int ni_ = 0; ni_ < 2; ++ni_) { \
            v4f a_ = MFMA8(KF[mi_][0], qf[ni_][0], Z4v); \
            _Pragma("unroll") \
            for (int kc_ = 1; kc_ < 4; ++kc_) \
                a_ = MFMA8(KF[mi_][kc_], qf[ni_][kc_], a_); \
            SC[mi_][ni_] = a_; \
        } \
}

// softmax(SC_IN) hand-interleaved with the 16 S-MFMAs of the next tile.
#define FUSED(SC_IN, KF, SC_OUT) { \
    float e0_, e1_, e2_, e3_; \
    int pk00_, pk10_, pk01_, pk11_; \
    SC_OUT[0][0] = MFMA8(KF[0][0], qf[0][0], Z4v); \
    SC_OUT[0][1] = MFMA8(KF[0][0], qf[1][0], Z4v); \
    e0_ = EXP2(SC_IN[0][0][0]); e1_ = EXP2(SC_IN[0][0][1]); \
    e2_ = EXP2(SC_IN[0][0][2]); e3_ = EXP2(SC_IN[0][0][3]); \
    SC_OUT[0][0] = MFMA8(KF[0][1], qf[0][1], SC_OUT[0][0]); \
    SC_OUT[0][1] = MFMA8(KF[0][1], qf[1][1], SC_OUT[0][1]); \
    lpart[0] += (e0_ + e1_) + (e2_ + e3_); \
    PK8(e0_, e1_, e2_, e3_, pk00_) \
    SC_OUT[0][0] = MFMA8(KF[0][2], qf[0][2], SC_OUT[0][0]); \
    SC_OUT[0][1] = MFMA8(KF[0][2], qf[1][2], SC_OUT[0][1]); \
    e0_ = EXP2(SC_IN[1][0][0]); e1_ = EXP2(SC_IN[1][0][1]); \
    e2_ = EXP2(SC_IN[1][0][2]); e3_ = EXP2(SC_IN[1][0][3]); \
    SC_OUT[0][0] = MFMA8(KF[0][3], qf[0][3], SC_OUT[0][0]); \
    SC_OUT[0][1] = MFMA8(KF[0][3], qf[1][3], SC_OUT[0][1]); \
    lpart[0] += (e0_ + e1_) + (e2_ + e3_); \
    PK8(e0_, e1_, e2_, e3_, pk10_) \
    SC_OUT[1][0] = MFMA8(KF[1][0], qf[0][0], Z4v); \
    SC_OUT[1][1] = MFMA8(KF[1][0], qf[1][0], Z4v); \
    MKPF8(0, pk00_, pk10_) \
    SC_OUT[1][0] = MFMA8(KF[1][1], qf[0][1], SC_OUT[1][0]); \
    SC_OUT[1][1] = MFMA8(KF[1][1], qf[1][1], SC_OUT[1][1]); \
    e0_ = EXP2(SC_IN[0][1][0]); e1_ = EXP2(SC_IN[0][1][1]); \
    e2_ = EXP2(SC_IN[0][1][2]); e3_ = EXP2(SC_IN[0][1][3]); \
    SC_OUT[1][0] = MFMA8(KF[1][2], qf[0][2], SC_OUT[1][0]); \
    SC_OUT[1][1] = MFMA8(KF[1][2], qf[1][2], SC_OUT[1][1]); \
    lpart[1] += (e0_ + e1_) + (e2_ + e3_); \
    PK8(e0_, e1_, e2_, e3_, pk01_) \
    SC_OUT[1][0] = MFMA8(KF[1][3], qf[0][3], SC_OUT[1][0]); \
    SC_OUT[1][1] = MFMA8(KF[1][3], qf[1][3], SC_OUT[1][1]); \
    e0_ = EXP2(SC_IN[1][1][0]); e1_ = EXP2(SC_IN[1][1][1]); \
    e2_ = EXP2(SC_IN[1][1][2]); e3_ = EXP2(SC_IN[1][1][3]); \
    lpart[1] += (e0_ + e1_) + (e2_ + e3_); \
    PK8(e0_, e1_, e2_, e3_, pk11_) \
    MKPF8(1, pk01_, pk11_) \
}

// T5: boost wave priority across the pure-MFMA PV cluster.
#define PVOP { \
    __builtin_amdgcn_s_setprio(1); \
    _Pragma("unroll") \
    for (int ni_ = 0; ni_ < 2; ++ni_) \
        _Pragma("unroll") \
        for (int cb_ = 0; cb_ < 8; ++cb_) \
            oacc[cb_][ni_] = MFMA8(vf[cb_], pf[ni_], oacc[cb_][ni_]); \
    __builtin_amdgcn_s_setprio(0); \
}

__global__ __launch_bounds__(256, 2) void attn_kernel(
    const unsigned char* __restrict__ qf8, const unsigned char* __restrict__ kt8,
    const unsigned char* __restrict__ vt8, const float* __restrict__ x,
    const float* __restrict__ gamma, float* __restrict__ out)
{
    __shared__ float red[32 * 132];   // O reduction scratch [n][c] (+pad)
    __shared__ float l_s[4][32];

    const int bid = blockIdx.x;
    const int bb  = bid & 7;
    const int s   = bid >> 3;        // n-strip 0..127 (32 rows each)
    const int n0  = s * 32;
    const int tid = threadIdx.x;
    const int w    = tid >> 6;       // wave = m-quarter owner
    const int lane = tid & 63;
    const int quad = lane >> 4;
    const int l16  = lane & 15;

    // ---- Q fragments (n=32 strip): fp8, 16 VGPR, iteration-invariant
    u64 qf[2][4];
    {
        const unsigned char* qb = qf8 + (size_t)(bb * 128 + s) * 4096 + lane * 16;
        #pragma unroll
        for (int ni = 0; ni < 2; ++ni)
            #pragma unroll
            for (int kcp = 0; kcp < 2; ++kcp) {
                uint4 u = *(const uint4*)(qb + (ni * 2 + kcp) * 1024);
                SPLIT16(u, qf[ni][kcp * 2], qf[ni][kcp * 2 + 1])
            }
    }

    v4f oacc[8][2];  // [cb][ni] partial O over this wave's 32-m subset
    #pragma unroll
    for (int i = 0; i < 8; ++i)
        #pragma unroll
        for (int j = 0; j < 2; ++j)
            oacc[i][j] = (v4f){0.f, 0.f, 0.f, 0.f};
    float lpart[2] = {0.f, 0.f};
    const v4f Z4v = {0.f, 0.f, 0.f, 0.f};

    const int la = ((((quad & 1) << 1) << 4) + l16) << 2;  // bpermute byte idx
    const int lb = la + 64;

    const unsigned char* kbase = kt8 + (size_t)(bb * 32) * 16384 + w * 4096 + lane * 16;
    const unsigned char* vbase = vt8 + (size_t)(bb * 32) * 16384 + w * 1024 + lane * 16;

    u64 kfA[2][4], kfB[2][4], vf[8], pf[2];
    v4f sc0[2][2], sc1[2][2];

    LOADK(kfA, 0)
    LOADV(0)
    LOADK(kfB, 1)
    SCOMP0(kfA, sc0)                 // S(0)

    for (int it = 0; it < 32; it += 2) {
        LOADK(kfA, (it + 2) & 31)    // K(t+2) in flight across this half-step
        FUSED(sc0, kfB, sc1)         // softmax(t) || S(t+1)
        PVOP                          // PV(t), consumes vf = V(t)
        LOADV((it + 1) & 31)
        LOADK(kfB, (it + 3) & 31)
        FUSED(sc1, kfA, sc0)         // softmax(t+1) || S(t+2)
        PVOP                          // PV(t+1)
        LOADV((it + 2) & 31)
    }

    // ---- softmax denominators (per-wave partials over its 32-m subset)
    #pragma unroll
    for (int ni = 0; ni < 2; ++ni) {
        float r = lpart[ni];
        r += __shfl_xor(r, 16);
        r += __shfl_xor(r, 32);
        if (lane < 16) l_s[w][ni * 16 + lane] = r;
    }

    // ---- O reduction across the 4 m-quarter waves
    for (int rw = 0; rw < 4; ++rw) {
        if (w == rw) {
            #pragma unroll
            for (int cb = 0; cb < 8; ++cb)
                #pragma unroll
                for (int ni = 0; ni < 2; ++ni) {
                    float* p = &red[(ni * 16 + l16) * 132 + cb * 16 + quad * 4];
                    if (rw == 0) *(v4f*)p = oacc[cb][ni];
                    else {
                        v4f tv = *(const v4f*)p;
                        tv += oacc[cb][ni];
                        *(v4f*)p = tv;
                    }
                }
        }
        __syncthreads();
    }

    // ---- epilogue: out = gamma * O / l + x  (thread: n = tid&31, c-group = tid>>5)
    const float g = gamma[0];
    const int   n = tid & 31;
    const int  cg = tid >> 5;        // 0..7
    const float li = 1.0f / (((l_s[0][n] + l_s[1][n]) + (l_s[2][n] + l_s[3][n])));
    #pragma unroll
    for (int j = 0; j < 16; ++j) {
        const int c = cg * 16 + j;
        const size_t idx = ((size_t)(bb * C_ + c)) * N_ + n0 + n;
        out[idx] = g * red[n * 132 + c] * li + x[idx];
    }
}

// ---------------------------------------------------------------------------
extern "C" void kernel_launch(void* const* d_in, const int* in_sizes, int n_in,
                              void* d_out, int out_size, void* d_ws, size_t ws_size,
                              hipStream_t stream)
{
    (void)in_sizes; (void)n_in; (void)out_size; (void)ws_size;
    const float* x     = (const float*)d_in[0];
    const float* dw_q  = (const float*)d_in[1];
    const float* pw_q  = (const float*)d_in[2];
    const float* dw_k  = (const float*)d_in[3];
    const float* pw_k  = (const float*)d_in[4];
    const float* dw_v  = (const float*)d_in[5];
    const float* pw_v  = (const float*)d_in[6];
    const float* gamma = (const float*)d_in[7];
    float* out = (float*)d_out;

    unsigned char* qf8 = (unsigned char*)d_ws;                         // 4 MB
    unsigned char* kt8 = qf8 + (size_t)B_ * N_ * C_;                   // +4 MB
    unsigned char* vt8 = kt8 + (size_t)B_ * N_ * C_;                   // +4 MB

    proj_kernel<<<dim3(768), dim3(256), 0, stream>>>(
        x, dw_q, pw_q, dw_k, pw_k, dw_v, pw_v, qf8, kt8, vt8);
    attn_kernel<<<dim3(1024), dim3(256), 0, stream>>>(
        qf8, kt8, vt8, x, gamma, out);
}